// Round 4
// baseline (725.804 us; speedup 1.0000x reference)
//
#include <hip/hip_runtime.h>
#include <math.h>

#define DIM 1024
#define FFN_DIM 4096
#define HEADS 8
#define HD 128
#define BB 2
#define LL 2048
#define NROWS (BB*LL)   // 4096

typedef __attribute__((ext_vector_type(8))) short bf16x8;
typedef __attribute__((ext_vector_type(4))) short bf16x4;
typedef __attribute__((ext_vector_type(2))) short bf16x2;
typedef __attribute__((ext_vector_type(4))) float f32x4;

__device__ inline short f2bf(float f) {
    unsigned u = __builtin_bit_cast(unsigned, f);
    unsigned r = (u + 0x7FFFu + ((u >> 16) & 1u)) >> 16;
    return (short)r;
}
__device__ inline float bf2f(short s) {
    unsigned u = ((unsigned)(unsigned short)s) << 16;
    return __builtin_bit_cast(float, u);
}

__device__ __forceinline__ void gl_lds16(const void* g, void* l) {
    __builtin_amdgcn_global_load_lds(
        (const __attribute__((address_space(1))) unsigned int*)g,
        (__attribute__((address_space(3))) unsigned int*)l, 16, 0, 0);
}

// ---------------- LayerNorm (one block per row of 1024) -> bf16 out ----------------
__global__ __launch_bounds__(256) void ln_kernel_bf(
    const float* __restrict__ x, const float* __restrict__ w,
    const float* __restrict__ b, short* __restrict__ out)
{
    int row = blockIdx.x;
    int tid = threadIdx.x;
    const float* xr = x + (size_t)row * DIM;
    float4 v = *(const float4*)(xr + tid * 4);
    float s  = v.x + v.y + v.z + v.w;
    float ss = v.x*v.x + v.y*v.y + v.z*v.z + v.w*v.w;
    #pragma unroll
    for (int o = 32; o > 0; o >>= 1) { s += __shfl_down(s, o); ss += __shfl_down(ss, o); }
    __shared__ float red[10];
    int wid = tid >> 6;
    if ((tid & 63) == 0) { red[wid] = s; red[4 + wid] = ss; }
    __syncthreads();
    if (tid == 0) {
        float t  = red[0] + red[1] + red[2] + red[3];
        float t2 = red[4] + red[5] + red[6] + red[7];
        float mu  = t * (1.f / DIM);
        float var = t2 * (1.f / DIM) - mu * mu;
        red[8] = mu; red[9] = rsqrtf(var + 1e-5f);
    }
    __syncthreads();
    float mu = red[8], rs = red[9];
    float4 wv = *(const float4*)(w + tid * 4);
    float4 bv = *(const float4*)(b + tid * 4);
    bf16x4 o;
    o[0] = f2bf((v.x - mu) * rs * wv.x + bv.x);
    o[1] = f2bf((v.y - mu) * rs * wv.y + bv.y);
    o[2] = f2bf((v.z - mu) * rs * wv.z + bv.z);
    o[3] = f2bf((v.w - mu) * rs * wv.w + bv.w);
    *(bf16x4*)(out + (size_t)row * DIM + tid * 4) = o;
}

// ---------------- generic fp32(R,C) -> bf16 transpose (C,R), batched ----------------
__global__ __launch_bounds__(256) void transpose_cvt(
    const float* __restrict__ in, short* __restrict__ out,
    int R, int C, size_t ibs, size_t obs)
{
    __shared__ float t[32][33];
    int bz = blockIdx.z;
    int r0 = blockIdx.y * 32, c0 = blockIdx.x * 32;
    int tx = threadIdx.x & 31, ty = threadIdx.x >> 5;   // ty 0..7
    const float* ip = in + (size_t)bz * ibs;
    short* op = out + (size_t)bz * obs;
    #pragma unroll
    for (int i = 0; i < 4; ++i)
        t[ty + i * 8][tx] = ip[(size_t)(r0 + ty + i * 8) * C + c0 + tx];
    __syncthreads();
    #pragma unroll
    for (int i = 0; i < 4; ++i)
        op[(size_t)(c0 + ty + i * 8) * R + r0 + tx] = f2bf(t[tx][ty + i * 8]);
}

// ---------------- Vb bf16 (NROWS,DIM) -> Vt bf16 [bh][v][l] ----------------
__global__ __launch_bounds__(256) void vt_cvt(
    const short* __restrict__ Vb, short* __restrict__ Vt)
{
    __shared__ short t[32][34];
    int r0 = blockIdx.y * 32, c0 = blockIdx.x * 32;   // r: global row (b*LL+l), c: h*HD+v
    int tx = threadIdx.x & 31, ty = threadIdx.x >> 5;
    #pragma unroll
    for (int i = 0; i < 4; ++i)
        t[ty + i * 8][tx] = Vb[(size_t)(r0 + ty + i * 8) * DIM + c0 + tx];
    __syncthreads();
    int b = r0 >> 11;
    int l = (r0 & (LL - 1));
    #pragma unroll
    for (int i = 0; i < 4; ++i) {
        int c = c0 + ty + i * 8;
        int h = c >> 7, v = c & 127;
        Vt[(((size_t)(b * HEADS + h) * HD + v) << 11) + l + tx] = t[tx][ty + i * 8];
    }
}

// ---------------- pipelined bf16 MFMA GEMM: C = A(N,K) @ Bt(M,K)^T ----------------
// 256^2 tile (MI=8,NI=4): 8-phase schedule (m201 template). LDS split by K-half:
//   As[buf][kh][256 rows][32k], 64B rows, seg swizzle seg^=(row>>1)&3.
//   Phase = (kh, ma) quadrant: {ds_read subtile, 1 half-tile stage, barrier,
//   setprio+16 MFMA, barrier}; vmcnt(4) only at ends of phases 1 & 3.
// 128^2 tile (MI=4,NI=2): 4-buffer, 3-deep prefetch, counted vmcnt.
template<int EPI, int MI, int NI, int GX>
__global__ __launch_bounds__(512, 2) void gemm_pipe(
    const short* __restrict__ A, const short* __restrict__ Bt,
    void* __restrict__ Cv, const float* __restrict__ bias,
    const float* __restrict__ R_,
    void* __restrict__ P1, void* __restrict__ P2, void* __restrict__ P3,
    int N, int K, int M)
{
    constexpr int BM = 32 * MI;           // 256 or 128
    constexpr int BN = 64 * NI;           // 256 or 128
    constexpr int NBUF = (MI == 4) ? 4 : 2;
    __shared__ __align__(16) short As[NBUF][BM * 64];
    __shared__ __align__(16) short Bs[NBUF][BN * 64];
    int tid = threadIdx.x;
    int w = tid >> 6, lane = tid & 63;
    int q = lane >> 4, lr = lane & 15;
    int wr = w >> 2, wc = w & 3;          // 2 x 4 wave grid

    // XCD-aware bijective tile remap (all grids here are 256 blocks = 8*32)
    int id = blockIdx.y * GX + blockIdx.x;
    int xcd = id & 7, j = id >> 3;
    constexpr int rx_n = (GX >= 8) ? GX / 8 : 1;
    int tp = (GX * gridDim.y) >> 3;       // tiles per xcd
    int rh = tp >> 3;                     // region height (rw = 8)
    int lbx = j & 7, lby = j >> 3;
    int rx = xcd % rx_n, ry = xcd / rx_n;
    int bm = (ry * rh + lby) * BM;
    int bn = (rx * 8 + lbx) * BN;

    f32x4 acc[MI][NI];
    #pragma unroll
    for (int mi = 0; mi < MI; ++mi)
        #pragma unroll
        for (int ni = 0; ni < NI; ++ni) acc[mi][ni] = (f32x4){0.f, 0.f, 0.f, 0.f};

    int nk = K >> 6;

    if constexpr (MI == 8) {
        // ================= 8-phase 256^2 path =================
        int segoff = (q ^ ((lr >> 1) & 3)) << 3;   // lane-constant read swizzle (shorts)

        auto stageAh = [&](int bb, int kglob, int kh) {
            #pragma unroll
            for (int i = 0; i < 2; ++i) {
                int c = i * 512 + tid;             // 0..1023
                int row = c >> 2, seg = c & 3;
                gl_lds16(A + (size_t)(bm + row) * K + kglob + ((seg ^ ((row >> 1) & 3)) << 3),
                         &As[bb][kh * 8192 + c * 8]);
            }
        };
        auto stageBh = [&](int bb, int kglob, int kh) {
            #pragma unroll
            for (int i = 0; i < 2; ++i) {
                int c = i * 512 + tid;
                int row = c >> 2, seg = c & 3;
                gl_lds16(Bt + (size_t)(bn + row) * K + kglob + ((seg ^ ((row >> 1) & 3)) << 3),
                         &Bs[bb][kh * 8192 + c * 8]);
            }
        };
        auto ldA = [&](int b, int kh, int ma, bf16x8* af) {
            #pragma unroll
            for (int mi = 0; mi < 4; ++mi)
                af[mi] = *(const bf16x8*)&As[b][kh * 8192 +
                         (wr * 128 + ma * 64 + mi * 16 + lr) * 32 + segoff];
        };
        auto ldB = [&](int b, int kh, bf16x8* bq) {
            #pragma unroll
            for (int ni = 0; ni < 4; ++ni)
                bq[ni] = *(const bf16x8*)&Bs[b][kh * 8192 +
                         (wc * 64 + ni * 16 + lr) * 32 + segoff];
        };

        // prologue: tile 0, issue order Akh0,Bkh0,Akh1,Bkh1; wait first two halves
        stageAh(0, 0, 0); stageBh(0, 0, 0); stageAh(0, 32, 1); stageBh(0, 32, 1);
        asm volatile("s_waitcnt vmcnt(4)\ns_barrier" ::: "memory");

        #pragma unroll 1
        for (int kt = 0; kt < nk; ++kt) {
            int b = kt & 1;
            int kn = (kt + 1) << 6;
            bool pf = (kt + 1 < nk);
            bf16x8 af[4], bq[4];
            // ---- phase 0: kh0, ma0 ----
            ldB(b, 0, bq); ldA(b, 0, 0, af);
            if (pf) stageAh(b ^ 1, kn, 0);
            asm volatile("s_barrier" ::: "memory");
            __builtin_amdgcn_s_setprio(1);
            #pragma unroll
            for (int mi = 0; mi < 4; ++mi)
                #pragma unroll
                for (int ni = 0; ni < 4; ++ni)
                    acc[mi][ni] = __builtin_amdgcn_mfma_f32_16x16x32_bf16(af[mi], bq[ni], acc[mi][ni], 0, 0, 0);
            __builtin_amdgcn_s_setprio(0);
            asm volatile("s_barrier" ::: "memory");
            // ---- phase 1: kh0, ma1 ----
            ldA(b, 0, 1, af);
            if (pf) stageBh(b ^ 1, kn, 0);
            asm volatile("s_barrier" ::: "memory");
            __builtin_amdgcn_s_setprio(1);
            #pragma unroll
            for (int mi = 0; mi < 4; ++mi)
                #pragma unroll
                for (int ni = 0; ni < 4; ++ni)
                    acc[4 + mi][ni] = __builtin_amdgcn_mfma_f32_16x16x32_bf16(af[mi], bq[ni], acc[4 + mi][ni], 0, 0, 0);
            __builtin_amdgcn_s_setprio(0);
            if (pf) asm volatile("s_waitcnt vmcnt(4)\ns_barrier" ::: "memory");
            else    asm volatile("s_waitcnt vmcnt(0)\ns_barrier" ::: "memory");
            // ---- phase 2: kh1, ma0 ----
            ldB(b, 1, bq); ldA(b, 1, 0, af);
            if (pf) stageAh(b ^ 1, kn + 32, 1);
            asm volatile("s_barrier" ::: "memory");
            __builtin_amdgcn_s_setprio(1);
            #pragma unroll
            for (int mi = 0; mi < 4; ++mi)
                #pragma unroll
                for (int ni = 0; ni < 4; ++ni)
                    acc[mi][ni] = __builtin_amdgcn_mfma_f32_16x16x32_bf16(af[mi], bq[ni], acc[mi][ni], 0, 0, 0);
            __builtin_amdgcn_s_setprio(0);
            asm volatile("s_barrier" ::: "memory");
            // ---- phase 3: kh1, ma1 ----
            ldA(b, 1, 1, af);
            if (pf) stageBh(b ^ 1, kn + 32, 1);
            asm volatile("s_barrier" ::: "memory");
            __builtin_amdgcn_s_setprio(1);
            #pragma unroll
            for (int mi = 0; mi < 4; ++mi)
                #pragma unroll
                for (int ni = 0; ni < 4; ++ni)
                    acc[4 + mi][ni] = __builtin_amdgcn_mfma_f32_16x16x32_bf16(af[mi], bq[ni], acc[4 + mi][ni], 0, 0, 0);
            __builtin_amdgcn_s_setprio(0);
            if (pf) asm volatile("s_waitcnt vmcnt(4)\ns_barrier" ::: "memory");
            else    asm volatile("s_barrier" ::: "memory");
        }
    } else {
        // ================= 128^2 path: 4-buffer, 3-deep prefetch =================
        int srow = tid >> 3;                  // staging: row within 64-row group
        int sseg = tid & 7;                   // 16B segment 0..7
        auto stageA = [&](int bb, int k0) {
            #pragma unroll
            for (int i = 0; i < BM / 64; ++i) {
                int row = i * 64 + srow;
                gl_lds16(A + (size_t)(bm + row) * K + k0 + ((sseg ^ (row & 7)) << 3),
                         &As[bb][(i * 512 + tid) * 8]);
            }
        };
        auto stageB = [&](int bb, int k0) {
            #pragma unroll
            for (int i = 0; i < BN / 64; ++i) {
                int row = i * 64 + srow;
                gl_lds16(Bt + (size_t)(bn + row) * K + k0 + ((sseg ^ (row & 7)) << 3),
                         &Bs[bb][(i * 512 + tid) * 8]);
            }
        };
        int aoff = (wr * (BM / 2) + lr) * 64;     // shorts
        int boff = (wc * (BN / 4) + lr) * 64;
        int seg0 = ((q ^ (lr & 7)) << 3);         // khalf0 segment (shorts)
        int seg1 = (((4 + q) ^ (lr & 7)) << 3);   // khalf1
        auto compute_half = [&](const short* as, const short* bs, int seg) {
            bf16x8 af[MI], bfr[NI];
            #pragma unroll
            for (int mi = 0; mi < MI; ++mi)
                af[mi] = *(const bf16x8*)&as[aoff + mi * 1024 + seg];
            #pragma unroll
            for (int ni = 0; ni < NI; ++ni)
                bfr[ni] = *(const bf16x8*)&bs[boff + ni * 1024 + seg];
            __builtin_amdgcn_s_setprio(1);
            #pragma unroll
            for (int mi = 0; mi < MI; ++mi)
                #pragma unroll
                for (int ni = 0; ni < NI; ++ni)
                    acc[mi][ni] = __builtin_amdgcn_mfma_f32_16x16x32_bf16(af[mi], bfr[ni], acc[mi][ni], 0, 0, 0);
            __builtin_amdgcn_s_setprio(0);
        };

        #pragma unroll
        for (int d = 0; d < 3; ++d) {
            stageA(d, d << 6);
            stageB(d, d << 6);
        }
        #pragma unroll 1
        for (int kt = 0; kt < nk; ++kt) {
            int b = kt & 3;
            if (kt + 3 < nk) {
                int bb = (kt + 3) & 3;
                stageA(bb, (kt + 3) << 6);
                stageB(bb, (kt + 3) << 6);
            }
            int rem = nk - 1 - kt;
            if (rem >= 3)      asm volatile("s_waitcnt vmcnt(12)\ns_barrier" ::: "memory");
            else if (rem == 2) asm volatile("s_waitcnt vmcnt(8)\ns_barrier" ::: "memory");
            else if (rem == 1) asm volatile("s_waitcnt vmcnt(4)\ns_barrier" ::: "memory");
            else               asm volatile("s_waitcnt vmcnt(0)\ns_barrier" ::: "memory");
            compute_half(As[b], Bs[b], seg0);
            compute_half(As[b], Bs[b], seg1);
            asm volatile("s_barrier" ::: "memory");
        }
    }

    if constexpr (EPI == 4) {
        int sel = bn >> 10;                        // block-uniform (BN <= 1024)
        int row_base = bm + wr * (BM / 2) + q * 4; // +mi*16+r
        int l0 = row_base & (LL - 1);              // same b for whole block
        #pragma unroll
        for (int ni = 0; ni < NI; ++ni) {
            int col = bn + wc * (BN / 4) + ni * 16 + lr;
            int cq = col & (DIM - 1);
            if (sel <= 1) {
                int jj = (col & 127) >> 1;
                float lb = log2f((2.f * jj + 51.2f) / 179.2f);
                if (sel == 1) lb = -lb;            // downscale for K
                float invf = exp2f(-(float)jj * (13.287712379549449f / 64.f));
                float snb, cnb;
                sincosf((float)l0 * invf, &snb, &cnb);
                float scb = exp2f(lb * (float)l0 * (1.f / 512.f));
                float s1, c1, s16, c16;
                __sincosf(invf, &s1, &c1);
                __sincosf(16.f * invf, &s16, &c16);
                float st1 = exp2f(lb * (1.f / 512.f));
                float st16 = exp2f(lb * (16.f / 512.f));
                short* Ob = (short*)(sel == 0 ? Cv : P1);
                #pragma unroll
                for (int mi = 0; mi < MI; ++mi) {
                    float cr = cnb, sr = snb, sv = scb;
                    #pragma unroll
                    for (int r = 0; r < 4; ++r) {
                        float cs = cr * sv, ssn = sr * sv;
                        float v = acc[mi][ni][r];
                        float p = __shfl_xor(v, 1);
                        float o = (lr & 1) ? (v * cs + p * ssn) : (v * cs - p * ssn);
                        Ob[(size_t)(row_base + mi * 16 + r) * DIM + cq] = f2bf(o);
                        if (r < 3) {
                            float crn = cr * c1 - sr * s1;
                            sr = sr * c1 + cr * s1; cr = crn;
                            sv *= st1;
                        }
                    }
                    float cbn = cnb * c16 - snb * s16;
                    snb = snb * c16 + cnb * s16; cnb = cbn;
                    scb *= st16;
                }
            } else if (sel == 2) {
                short* Vb = (short*)P2;
                #pragma unroll
                for (int mi = 0; mi < MI; ++mi)
                    #pragma unroll
                    for (int r = 0; r < 4; ++r)
                        Vb[(size_t)(row_base + mi * 16 + r) * DIM + cq] = f2bf(acc[mi][ni][r]);
            } else {
                short* Gb = (short*)P3;
                #pragma unroll
                for (int mi = 0; mi < MI; ++mi)
                    #pragma unroll
                    for (int r = 0; r < 4; ++r)
                        Gb[(size_t)(row_base + mi * 16 + r) * DIM + cq] = f2bf(acc[mi][ni][r]);
            }
        }
        return;
    }

    float* Cf = (float*)Cv;
    short* Cs = (short*)Cv;
    #pragma unroll
    for (int ni = 0; ni < NI; ++ni) {
        int col = bn + wc * (BN / 4) + ni * 16 + lr;
        float bi = 0.f;
        if constexpr (EPI == 1 || EPI == 2) bi = bias[col];
        #pragma unroll
        for (int mi = 0; mi < MI; ++mi) {
            int row0 = bm + wr * (BM / 2) + mi * 16 + q * 4;
            #pragma unroll
            for (int r = 0; r < 4; ++r) {
                size_t off = (size_t)(row0 + r) * M + col;
                float v = acc[mi][ni][r];
                if constexpr (EPI == 1) {
                    v += bi;
                    v = 0.5f * v * (1.f + erff(v * 0.70710678118654752f));
                    Cs[off] = f2bf(v);
                } else if constexpr (EPI == 2) {
                    Cf[off] = v + bi + R_[off];
                } else if constexpr (EPI == 3) {
                    Cf[off] = v + R_[off];
                } else {
                    Cf[off] = v;
                }
            }
        }
    }
}

// ---------------- retention: 8-wave parity-split, counted-vmcnt pipeline ----------------
#define PSTR 40
__global__ __launch_bounds__(512, 2) void retention_mfma2(
    const short* __restrict__ Qb, const short* __restrict__ Kb,
    const short* __restrict__ Vt, float* __restrict__ Y)
{
    __shared__ __align__(16) short Ks[2][64 * 128];   // 32 KB (also Y-combine scratch)
    __shared__ __align__(16) short Vs[2][128 * 64];   // 32 KB
    __shared__ __align__(16) short Ps[8][16 * PSTR];  // 10 KB
    int tid = threadIdx.x;
    int w = tid >> 6, lane = tid & 63;
    int q = lane >> 4, lr = lane & 15;
    int g = w >> 2;                        // tile-parity group
    int qw = w & 3;                        // Q sub-strip wave
    int bh = blockIdx.x;
    int b = bh >> 3, h = bh & 7;
    size_t bL = (size_t)b * LL;
    const short* Kbh = Kb + (bL << 10) + (h << 7);
    const short* Qbh = Qb + (bL << 10) + (h << 7);
    const short* Vbh = Vt + ((size_t)bh << 18);
    float* Ybh = Y + (bL << 10) + (h << 7);

    const float lg_lo = -3.4657359027997265f;
    const float lg_hi = -6.2383246250395075f;
    float gamma = 1.f - expf(lg_lo + (lg_hi - lg_lo) * ((float)h / 7.f));
    float logg = logf(gamma);
    float gm64 = expf(-64.f * logg);
    float rf[4];
    #pragma unroll
    for (int r = 0; r < 4; ++r) rf[r] = expf(logg * (float)(q * 4 + r));
    float cf0 = expf(-logg * (float)lr);
    float cf1 = expf(-logg * (float)(16 + lr));
    int dqlr = q * 4 - lr;

    int kr_l = lane >> 4;                  // 0..3
    int ks_l = lane & 15;                  // 16B seg in 256B row
    int vr_l = lane >> 3;                  // 0..7
    int vs_l = lane & 7;                   // 16B seg in 128B row

    auto stageKV = [&](int bb, int m0) {
        #pragma unroll
        for (int i = 0; i < 2; ++i) {
            int ch = w * 2 + i;            // 0..15
            int kr = ch * 4 + kr_l;        // 0..63
            gl_lds16(Kbh + ((size_t)(m0 + kr) << 10) + ((ks_l ^ (kr & 15)) << 3),
                     &Ks[bb][ch * 512]);
            int vr = ch * 8 + vr_l;        // 0..127
            gl_lds16(Vbh + ((size_t)vr << 11) + m0 + ((vs_l ^ (vr & 7)) << 3),
                     &Vs[bb][ch * 512]);
        }
    };

    #pragma unroll 1
    for (int pass = 0; pass < 2; ++pass) {
        int jt = pass ? (31 - blockIdx.y) : blockIdx.y;
        int l0w = jt * 64 + qw * 16;
        int ns = jt + 1;                   // 64-row K/V steps

        bf16x8 qf[4];
        {
            const short* qp = Qbh + ((size_t)(l0w + lr) << 10) + q * 8;
            #pragma unroll
            for (int es = 0; es < 4; ++es) qf[es] = *(const bf16x8*)(qp + es * 32);
        }
        f32x4 yacc[8];
        #pragma unroll
        for (int vt = 0; vt < 8; ++vt) yacc[vt] = (f32x4){0.f, 0.f, 0.f, 0.f};
        float tf = expf(logg * (float)(l0w - g * 32));

        stageKV(0, 0);

        #pragma unroll 1
        for (int s = 0; s < ns; ++s) {
            int buf = s & 1;
            if (s + 1 < ns) {
                stageKV(buf ^ 1, (s + 1) * 64);
                asm volatile("s_waitcnt vmcnt(4)\ns_barrier" ::: "memory");
            } else {
                asm volatile("s_waitcnt vmcnt(0)\ns_barrier" ::: "memory");
            }
            int m0 = s * 64 + g * 32;
            if (m0 <= l0w + 15) {
                int dt = l0w - m0;
                const short* ksub = &Ks[buf][g * 32 * 128];
                f32x4 sa0 = (f32x4){0.f,0.f,0.f,0.f};
                f32x4 sa1 = (f32x4){0.f,0.f,0.f,0.f};
                #pragma unroll
                for (int es = 0; es < 4; ++es) {
                    int slot = ((es * 4 + q) ^ lr) * 8;
                    bf16x8 bk0 = *(const bf16x8*)&ksub[lr * 128 + slot];
                    bf16x8 bk1 = *(const bf16x8*)&ksub[(16 + lr) * 128 + slot];
                    sa0 = __builtin_amdgcn_mfma_f32_16x16x32_bf16(qf[es], bk0, sa0, 0, 0, 0);
                    sa1 = __builtin_amdgcn_mfma_f32_16x16x32_bf16(qf[es], bk1, sa1, 0, 0, 0);
                }
                #pragma unroll
                for (int r = 0; r < 4; ++r) {
                    float p0 = sa0[r] * (rf[r] * cf0 * tf);
                    float p1 = sa1[r] * (rf[r] * cf1 * tf);
                    int d0 = dt + dqlr + r;
                    Ps[w][(q*4 + r) * PSTR + lr]      = (d0 >= 0)      ? f2bf(p0) : (short)0;
                    Ps[w][(q*4 + r) * PSTR + 16 + lr] = (d0 - 16 >= 0) ? f2bf(p1) : (short)0;
                }
                bf16x8 pa = *(const bf16x8*)&Ps[w][lr * PSTR + q * 8];
                #pragma unroll
                for (int vt = 0; vt < 8; ++vt) {
                    bf16x8 bv = *(const bf16x8*)&Vs[buf][(vt * 16 + lr) * 64 + (((g * 4 + q) ^ (lr & 7)) << 3)];
                    yacc[vt] = __builtin_amdgcn_mfma_f32_16x16x32_bf16(pa, bv, yacc[vt], 0, 0, 0);
                }
            }
            tf *= gm64;
            asm volatile("s_barrier" ::: "memory");
        }
        __syncthreads();
        // combine group partials via LDS scratch (reuse Ks; xor-swizzled, 2-way free)
        float* sc = (float*)&Ks[0][0] + qw * 2048;
        if (g) {
            #pragma unroll
            for (int vt = 0; vt < 8; ++vt)
                #pragma unroll
                for (int r = 0; r < 4; ++r)
                    sc[(q * 4 + r) * 128 + ((vt * 16 + lr) ^ (q * 8))] = yacc[vt][r];
        }
        __syncthreads();
        if (!g) {
            float* yp = Ybh + ((size_t)(l0w + q * 4) << 10) + lr;
            #pragma unroll
            for (int vt = 0; vt < 8; ++vt)
                #pragma unroll
                for (int r = 0; r < 4; ++r)
                    yp[((size_t)r << 10) + vt * 16] =
                        yacc[vt][r] + sc[(q * 4 + r) * 128 + ((vt * 16 + lr) ^ (q * 8))];
        }
        __syncthreads();
    }
}

// ---------------- groupnorm * swish-gate (bf16 G) -> bf16 out ----------------
__global__ __launch_bounds__(256) void gn_gate_kernel(
    const float* __restrict__ Y, const short* __restrict__ Gb,
    const float* __restrict__ w, const float* __restrict__ b,
    short* __restrict__ ybf)
{
    int tid = threadIdx.x;
    int wid = tid >> 6, lane = tid & 63;
    int grp = blockIdx.x * 4 + wid;
    int n = grp >> 3, h = grp & 7;
    size_t base = (size_t)n * DIM + h * HD + lane * 2;
    float2 y = *(const float2*)(Y + base);
    float s = y.x + y.y, ss = y.x * y.x + y.y * y.y;
    #pragma unroll
    for (int o = 32; o > 0; o >>= 1) { s += __shfl_down(s, o); ss += __shfl_down(ss, o); }
    s = __shfl(s, 0); ss = __shfl(ss, 0);
    float mu  = s * (1.f / HD);
    float var = ss * (1.f / HD) - mu * mu;
    float rs  = rsqrtf(var + 1e-5f);
    float2 wv = *(const float2*)(w + h * HD + lane * 2);
    float2 bv = *(const float2*)(b + h * HD + lane * 2);
    bf16x2 gv = *(const bf16x2*)(Gb + base);
    float gx = bf2f(gv[0]), gy = bf2f(gv[1]);
    float g0 = gx / (1.f + expf(-gx));
    float g1 = gy / (1.f + expf(-gy));
    bf16x2 o;
    o[0] = f2bf(((y.x - mu) * rs * wv.x + bv.x) * g0);
    o[1] = f2bf(((y.y - mu) * rs * wv.y + bv.y) * g1);
    *(bf16x2*)(ybf + base) = o;
}

extern "C" void kernel_launch(void* const* d_in, const int* in_sizes, int n_in,
                              void* d_out, int out_size, void* d_ws, size_t ws_size,
                              hipStream_t stream)
{
    const float* X0   = (const float*)d_in[0];
    const float* Wq   = (const float*)d_in[1];
    const float* Wk   = (const float*)d_in[2];
    const float* Wv   = (const float*)d_in[3];
    const float* WG   = (const float*)d_in[4];
    const float* WO   = (const float*)d_in[5];
    const float* gnw  = (const float*)d_in[6];
    const float* gnb  = (const float*)d_in[7];
    const float* ln1w = (const float*)d_in[8];
    const float* ln1b = (const float*)d_in[9];
    const float* ln2w = (const float*)d_in[10];
    const float* ln2b = (const float*)d_in[11];
    const float* fw1  = (const float*)d_in[12];
    const float* fb1  = (const float*)d_in[13];
    const float* fw2  = (const float*)d_in[14];
    const float* fb2  = (const float*)d_in[15];

    float* ws = (float*)d_ws;
    const size_t U = (size_t)NROWS * DIM;    // 4M floats = 16 MB

    short* lnbf  = (short*)(ws + 0 * U);
    short* wqkvg = lnbf + (size_t)NROWS * DIM;
    short* Vt   = (short*)(ws + 1 * U);
    short* fw1t = (short*)(ws + 1 * U);
    short* fw2t = fw1t + (size_t)DIM * FFN_DIM;
    float* sY  = ws + 2 * U;
    short* h1   = (short*)(ws + 2 * U);              // 32 MB spans U2+U3
    short* Vb   = (short*)(ws + 3 * U);
    short* ybf  = (short*)(ws + 3 * U);
    short* wot  = ybf + (size_t)NROWS * DIM;
    short* Gb   = (short*)(ws + 4 * U);
    float* sXn = ws + 4 * U;                         // after gn_gate, Gb dead
    short* Qb   = (short*)(ws + 5 * U);
    short* Kb   = Qb + (size_t)NROWS * DIM;
    float* sX  = ws + 6 * U;

    for (int i = 0; i < 2; ++i) {
        const float* Xin = (i == 0) ? X0 : sX;
        float* Xout = (i == 1) ? (float*)d_out : sX;

        // LN1 -> bf16
        ln_kernel_bf<<<NROWS, 256, 0, stream>>>(Xin, ln1w + i * DIM, ln1b + i * DIM, lnbf);
        // weight transposes into one contiguous (4096,1024) Bt: [Wq|Wk|Wv|WG]
        dim3 tq(HD / 32, DIM / 32, HEADS);
        transpose_cvt<<<tq, 256, 0, stream>>>(Wq + (size_t)i * HEADS * DIM * HD, wqkvg + 0 * DIM * DIM, DIM, HD, (size_t)DIM * HD, (size_t)HD * DIM);
        transpose_cvt<<<tq, 256, 0, stream>>>(Wk + (size_t)i * HEADS * DIM * HD, wqkvg + 1 * DIM * DIM, DIM, HD, (size_t)DIM * HD, (size_t)HD * DIM);
        transpose_cvt<<<tq, 256, 0, stream>>>(Wv + (size_t)i * HEADS * DIM * HD, wqkvg + 2 * DIM * DIM, DIM, HD, (size_t)DIM * HD, (size_t)HD * DIM);
        dim3 tg(DIM / 32, DIM / 32, 1);
        transpose_cvt<<<tg, 256, 0, stream>>>(WG + (size_t)i * DIM * DIM, wqkvg + 3 * (size_t)DIM * DIM, DIM, DIM, 0, 0);
        // fused QKVG projection + xpos + bf16: writes Qb, Kb, Vb, Gb (256^2, 8-phase)
        dim3 gp4(4 * DIM / 256, NROWS / 256);   // (16,16)
        gemm_pipe<4, 8, 4, 16><<<gp4, 512, 0, stream>>>(lnbf, wqkvg, Qb, nullptr, nullptr, Kb, Vb, Gb, NROWS, DIM, 4 * DIM);
        // V transpose (bf16 -> bf16 [bh][v][l])
        dim3 vg(DIM / 32, NROWS / 32);
        vt_cvt<<<vg, 256, 0, stream>>>(Vb, Vt);
        // retention -> sY (8-wave parity-split)
        dim3 rg(16, 16);
        retention_mfma2<<<rg, 512, 0, stream>>>(Qb, Kb, Vt, sY);
        // groupnorm + gate -> ybf (overwrites Vb region; Vb dead)
        gn_gate_kernel<<<NROWS * HEADS / 4, 256, 0, stream>>>(sY, Gb, gnw + i * DIM, gnb + i * DIM, ybf);
        // W_O + residual -> sXn (Gb dead)
        transpose_cvt<<<tg, 256, 0, stream>>>(WO + (size_t)i * DIM * DIM, wot, DIM, DIM, 0, 0);
        dim3 gp(DIM / 128, NROWS / 128);   // (8,32)
        gemm_pipe<3, 4, 2, 8><<<gp, 512, 0, stream>>>(ybf, wot, sXn, nullptr, Xin, nullptr, nullptr, nullptr, NROWS, DIM, DIM);
        // LN2 -> lnbf
        ln_kernel_bf<<<NROWS, 256, 0, stream>>>(sXn, ln2w + i * DIM, ln2b + i * DIM, lnbf);
        // FFN weight transposes (U1 free: Vt dead after retention)
        dim3 t1(FFN_DIM / 32, DIM / 32, 1);
        transpose_cvt<<<t1, 256, 0, stream>>>(fw1 + (size_t)i * DIM * FFN_DIM, fw1t, DIM, FFN_DIM, 0, 0);
        dim3 t2(DIM / 32, FFN_DIM / 32, 1);
        transpose_cvt<<<t2, 256, 0, stream>>>(fw2 + (size_t)i * FFN_DIM * DIM, fw2t, FFN_DIM, DIM, 0, 0);
        // FFN1: + bias + gelu -> h1 bf16 (256^2, 8-phase)
        dim3 gf1(FFN_DIM / 256, NROWS / 256);   // (16,16)
        gemm_pipe<1, 8, 4, 16><<<gf1, 512, 0, stream>>>(lnbf, fw1t, h1, fb1 + i * FFN_DIM, nullptr, nullptr, nullptr, nullptr, NROWS, DIM, FFN_DIM);
        // FFN2: + bias + residual -> Xout fp32
        dim3 gf2(DIM / 128, NROWS / 128);       // (8,32)
        gemm_pipe<2, 4, 2, 8><<<gf2, 512, 0, stream>>>(h1, fw2t, Xout, fb2 + i * DIM, sXn, nullptr, nullptr, nullptr, NROWS, FFN_DIM, DIM);
    }
}

// Round 5
// 718.198 us; speedup vs baseline: 1.0106x; 1.0106x over previous
//
#include <hip/hip_runtime.h>
#include <math.h>

#define DIM 1024
#define FFN_DIM 4096
#define HEADS 8
#define HD 128
#define BB 2
#define LL 2048
#define NROWS (BB*LL)   // 4096

typedef __attribute__((ext_vector_type(8))) short bf16x8;
typedef __attribute__((ext_vector_type(4))) short bf16x4;
typedef __attribute__((ext_vector_type(2))) short bf16x2;
typedef __attribute__((ext_vector_type(4))) float f32x4;

__device__ inline short f2bf(float f) {
    unsigned u = __builtin_bit_cast(unsigned, f);
    unsigned r = (u + 0x7FFFu + ((u >> 16) & 1u)) >> 16;
    return (short)r;
}
__device__ inline float bf2f(short s) {
    unsigned u = ((unsigned)(unsigned short)s) << 16;
    return __builtin_bit_cast(float, u);
}

__device__ __forceinline__ void gl_lds16(const void* g, void* l) {
    __builtin_amdgcn_global_load_lds(
        (const __attribute__((address_space(1))) unsigned int*)g,
        (__attribute__((address_space(3))) unsigned int*)l, 16, 0, 0);
}

// ---------------- xpos rotary tables: tq/tk[l][j] = (cos*s, sin*s) ----------------
__global__ __launch_bounds__(256) void xpos_tables(float2* __restrict__ tq,
                                                   float2* __restrict__ tk)
{
    int idx = blockIdx.x * 256 + threadIdx.x;   // l*64 + j
    int j = idx & 63, l = idx >> 6;
    float lb = log2f((2.f * j + 51.2f) / 179.2f);
    float invf = exp2f(-(float)j * (13.287712379549449f / 64.f));
    float s, c;
    sincosf((float)l * invf, &s, &c);
    float scu = exp2f(lb * (float)l * (1.f / 512.f));
    float scd = exp2f(-lb * (float)l * (1.f / 512.f));
    tq[idx] = make_float2(c * scu, s * scu);
    tk[idx] = make_float2(c * scd, s * scd);
}

// ---------------- LayerNorm (one block per row of 1024) -> bf16 out ----------------
__global__ __launch_bounds__(256) void ln_kernel_bf(
    const float* __restrict__ x, const float* __restrict__ w,
    const float* __restrict__ b, short* __restrict__ out)
{
    int row = blockIdx.x;
    int tid = threadIdx.x;
    const float* xr = x + (size_t)row * DIM;
    float4 v = *(const float4*)(xr + tid * 4);
    float s  = v.x + v.y + v.z + v.w;
    float ss = v.x*v.x + v.y*v.y + v.z*v.z + v.w*v.w;
    #pragma unroll
    for (int o = 32; o > 0; o >>= 1) { s += __shfl_down(s, o); ss += __shfl_down(ss, o); }
    __shared__ float red[10];
    int wid = tid >> 6;
    if ((tid & 63) == 0) { red[wid] = s; red[4 + wid] = ss; }
    __syncthreads();
    if (tid == 0) {
        float t  = red[0] + red[1] + red[2] + red[3];
        float t2 = red[4] + red[5] + red[6] + red[7];
        float mu  = t * (1.f / DIM);
        float var = t2 * (1.f / DIM) - mu * mu;
        red[8] = mu; red[9] = rsqrtf(var + 1e-5f);
    }
    __syncthreads();
    float mu = red[8], rs = red[9];
    float4 wv = *(const float4*)(w + tid * 4);
    float4 bv = *(const float4*)(b + tid * 4);
    bf16x4 o;
    o[0] = f2bf((v.x - mu) * rs * wv.x + bv.x);
    o[1] = f2bf((v.y - mu) * rs * wv.y + bv.y);
    o[2] = f2bf((v.z - mu) * rs * wv.z + bv.z);
    o[3] = f2bf((v.w - mu) * rs * wv.w + bv.w);
    *(bf16x4*)(out + (size_t)row * DIM + tid * 4) = o;
}

// ---------------- generic fp32(R,C) -> bf16 transpose (C,R), batched ----------------
__global__ __launch_bounds__(256) void transpose_cvt(
    const float* __restrict__ in, short* __restrict__ out,
    int R, int C, size_t ibs, size_t obs)
{
    __shared__ float t[32][33];
    int bz = blockIdx.z;
    int r0 = blockIdx.y * 32, c0 = blockIdx.x * 32;
    int tx = threadIdx.x & 31, ty = threadIdx.x >> 5;   // ty 0..7
    const float* ip = in + (size_t)bz * ibs;
    short* op = out + (size_t)bz * obs;
    #pragma unroll
    for (int i = 0; i < 4; ++i)
        t[ty + i * 8][tx] = ip[(size_t)(r0 + ty + i * 8) * C + c0 + tx];
    __syncthreads();
    #pragma unroll
    for (int i = 0; i < 4; ++i)
        op[(size_t)(c0 + ty + i * 8) * R + r0 + tx] = f2bf(t[tx][ty + i * 8]);
}

// ---------------- Vb bf16 (NROWS,DIM) -> Vt bf16 [bh][v][l] ----------------
__global__ __launch_bounds__(256) void vt_cvt(
    const short* __restrict__ Vb, short* __restrict__ Vt)
{
    __shared__ short t[32][34];
    int r0 = blockIdx.y * 32, c0 = blockIdx.x * 32;   // r: global row (b*LL+l), c: h*HD+v
    int tx = threadIdx.x & 31, ty = threadIdx.x >> 5;
    #pragma unroll
    for (int i = 0; i < 4; ++i)
        t[ty + i * 8][tx] = Vb[(size_t)(r0 + ty + i * 8) * DIM + c0 + tx];
    __syncthreads();
    int b = r0 >> 11;
    int l = (r0 & (LL - 1));
    #pragma unroll
    for (int i = 0; i < 4; ++i) {
        int c = c0 + ty + i * 8;
        int h = c >> 7, v = c & 127;
        Vt[(((size_t)(b * HEADS + h) * HD + v) << 11) + l + tx] = t[tx][ty + i * 8];
    }
}

// ---------------- pipelined bf16 MFMA GEMM: C = A(N,K) @ Bt(M,K)^T ----------------
// 256^2 tile (MI=8,NI=4): 8-phase schedule, 2 K-tiles per loop iter (literal
// buffer index). 128^2 tile (MI=4,NI=2): 4-buffer, 3-deep prefetch.
// EPI=4 (QKVG) uses precomputed xpos tables via bias(=TQ)/R_(=TK) args.
template<int EPI, int MI, int NI, int GX>
__global__ __launch_bounds__(512, 2) void gemm_pipe(
    const short* __restrict__ A, const short* __restrict__ Bt,
    void* __restrict__ Cv, const float* __restrict__ bias,
    const float* __restrict__ R_,
    void* __restrict__ P1, void* __restrict__ P2, void* __restrict__ P3,
    int N, int K, int M)
{
    constexpr int BM = 32 * MI;           // 256 or 128
    constexpr int BN = 64 * NI;           // 256 or 128
    constexpr int NBUF = (MI == 4) ? 4 : 2;
    __shared__ __align__(16) short As[NBUF][BM * 64];
    __shared__ __align__(16) short Bs[NBUF][BN * 64];
    int tid = threadIdx.x;
    int w = tid >> 6, lane = tid & 63;
    int q = lane >> 4, lr = lane & 15;
    int wr = w >> 2, wc = w & 3;          // 2 x 4 wave grid

    // XCD-aware bijective tile remap (all grids here are 256 blocks = 8*32)
    int id = blockIdx.y * GX + blockIdx.x;
    int xcd = id & 7, j = id >> 3;
    constexpr int rx_n = (GX >= 8) ? GX / 8 : 1;
    int tp = (GX * gridDim.y) >> 3;       // tiles per xcd
    int rh = tp >> 3;                     // region height (rw = 8)
    int lbx = j & 7, lby = j >> 3;
    int rx = xcd % rx_n, ry = xcd / rx_n;
    int bm = (ry * rh + lby) * BM;
    int bn = (rx * 8 + lbx) * BN;

    f32x4 acc[MI][NI];
    #pragma unroll
    for (int mi = 0; mi < MI; ++mi)
        #pragma unroll
        for (int ni = 0; ni < NI; ++ni) acc[mi][ni] = (f32x4){0.f, 0.f, 0.f, 0.f};

    int nk = K >> 6;

    if constexpr (MI == 8) {
        // ================= 8-phase 256^2 path =================
        int segoff = (q ^ ((lr >> 1) & 3)) << 3;   // lane-constant read swizzle (shorts)

        auto stageAh = [&](int bb, int kglob, int kh) {
            #pragma unroll
            for (int i = 0; i < 2; ++i) {
                int c = i * 512 + tid;             // 0..1023
                int row = c >> 2, seg = c & 3;
                gl_lds16(A + (size_t)(bm + row) * K + kglob + ((seg ^ ((row >> 1) & 3)) << 3),
                         &As[bb][kh * 8192 + c * 8]);
            }
        };
        auto stageBh = [&](int bb, int kglob, int kh) {
            #pragma unroll
            for (int i = 0; i < 2; ++i) {
                int c = i * 512 + tid;
                int row = c >> 2, seg = c & 3;
                gl_lds16(Bt + (size_t)(bn + row) * K + kglob + ((seg ^ ((row >> 1) & 3)) << 3),
                         &Bs[bb][kh * 8192 + c * 8]);
            }
        };
        auto ldA = [&](int b, int kh, int ma, bf16x8* af) {
            #pragma unroll
            for (int mi = 0; mi < 4; ++mi)
                af[mi] = *(const bf16x8*)&As[b][kh * 8192 +
                         (wr * 128 + ma * 64 + mi * 16 + lr) * 32 + segoff];
        };
        auto ldB = [&](int b, int kh, bf16x8* bq) {
            #pragma unroll
            for (int ni = 0; ni < 4; ++ni)
                bq[ni] = *(const bf16x8*)&Bs[b][kh * 8192 +
                         (wc * 64 + ni * 16 + lr) * 32 + segoff];
        };

        auto tile_body = [&](int b, int kt) {   // b is a literal at call sites
            int kn = (kt + 1) << 6;
            bool pf = (kt + 1 < nk);
            bf16x8 af[4], bq[4];
            // ---- phase 0: kh0, ma0 ----
            ldB(b, 0, bq); ldA(b, 0, 0, af);
            if (pf) stageAh(b ^ 1, kn, 0);
            asm volatile("s_barrier" ::: "memory");
            __builtin_amdgcn_s_setprio(1);
            #pragma unroll
            for (int mi = 0; mi < 4; ++mi)
                #pragma unroll
                for (int ni = 0; ni < 4; ++ni)
                    acc[mi][ni] = __builtin_amdgcn_mfma_f32_16x16x32_bf16(af[mi], bq[ni], acc[mi][ni], 0, 0, 0);
            __builtin_amdgcn_s_setprio(0);
            asm volatile("s_barrier" ::: "memory");
            // ---- phase 1: kh0, ma1 ----
            ldA(b, 0, 1, af);
            if (pf) stageBh(b ^ 1, kn, 0);
            asm volatile("s_barrier" ::: "memory");
            __builtin_amdgcn_s_setprio(1);
            #pragma unroll
            for (int mi = 0; mi < 4; ++mi)
                #pragma unroll
                for (int ni = 0; ni < 4; ++ni)
                    acc[4 + mi][ni] = __builtin_amdgcn_mfma_f32_16x16x32_bf16(af[mi], bq[ni], acc[4 + mi][ni], 0, 0, 0);
            __builtin_amdgcn_s_setprio(0);
            if (pf) asm volatile("s_waitcnt vmcnt(4)\ns_barrier" ::: "memory");
            else    asm volatile("s_waitcnt vmcnt(0)\ns_barrier" ::: "memory");
            // ---- phase 2: kh1, ma0 ----
            ldB(b, 1, bq); ldA(b, 1, 0, af);
            if (pf) stageAh(b ^ 1, kn + 32, 1);
            asm volatile("s_barrier" ::: "memory");
            __builtin_amdgcn_s_setprio(1);
            #pragma unroll
            for (int mi = 0; mi < 4; ++mi)
                #pragma unroll
                for (int ni = 0; ni < 4; ++ni)
                    acc[mi][ni] = __builtin_amdgcn_mfma_f32_16x16x32_bf16(af[mi], bq[ni], acc[mi][ni], 0, 0, 0);
            __builtin_amdgcn_s_setprio(0);
            asm volatile("s_barrier" ::: "memory");
            // ---- phase 3: kh1, ma1 ----
            ldA(b, 1, 1, af);
            if (pf) stageBh(b ^ 1, kn + 32, 1);
            asm volatile("s_barrier" ::: "memory");
            __builtin_amdgcn_s_setprio(1);
            #pragma unroll
            for (int mi = 0; mi < 4; ++mi)
                #pragma unroll
                for (int ni = 0; ni < 4; ++ni)
                    acc[4 + mi][ni] = __builtin_amdgcn_mfma_f32_16x16x32_bf16(af[mi], bq[ni], acc[4 + mi][ni], 0, 0, 0);
            __builtin_amdgcn_s_setprio(0);
            if (pf) asm volatile("s_waitcnt vmcnt(4)\ns_barrier" ::: "memory");
            else    asm volatile("s_barrier" ::: "memory");
        };

        // prologue: tile 0, issue order Akh0,Bkh0,Akh1,Bkh1; wait first two halves
        stageAh(0, 0, 0); stageBh(0, 0, 0); stageAh(0, 32, 1); stageBh(0, 32, 1);
        asm volatile("s_waitcnt vmcnt(4)\ns_barrier" ::: "memory");

        #pragma unroll 1
        for (int kt = 0; kt < nk; kt += 2) {
            tile_body(0, kt);
            tile_body(1, kt + 1);
        }
    } else {
        // ================= 128^2 path: 4-buffer, 3-deep prefetch =================
        int srow = tid >> 3;                  // staging: row within 64-row group
        int sseg = tid & 7;                   // 16B segment 0..7
        auto stageA = [&](int bb, int k0) {
            #pragma unroll
            for (int i = 0; i < BM / 64; ++i) {
                int row = i * 64 + srow;
                gl_lds16(A + (size_t)(bm + row) * K + k0 + ((sseg ^ (row & 7)) << 3),
                         &As[bb][(i * 512 + tid) * 8]);
            }
        };
        auto stageB = [&](int bb, int k0) {
            #pragma unroll
            for (int i = 0; i < BN / 64; ++i) {
                int row = i * 64 + srow;
                gl_lds16(Bt + (size_t)(bn + row) * K + k0 + ((sseg ^ (row & 7)) << 3),
                         &Bs[bb][(i * 512 + tid) * 8]);
            }
        };
        int aoff = (wr * (BM / 2) + lr) * 64;     // shorts
        int boff = (wc * (BN / 4) + lr) * 64;
        int seg0 = ((q ^ (lr & 7)) << 3);         // khalf0 segment (shorts)
        int seg1 = (((4 + q) ^ (lr & 7)) << 3);   // khalf1
        auto compute_half = [&](const short* as, const short* bs, int seg) {
            bf16x8 af[MI], bfr[NI];
            #pragma unroll
            for (int mi = 0; mi < MI; ++mi)
                af[mi] = *(const bf16x8*)&as[aoff + mi * 1024 + seg];
            #pragma unroll
            for (int ni = 0; ni < NI; ++ni)
                bfr[ni] = *(const bf16x8*)&bs[boff + ni * 1024 + seg];
            __builtin_amdgcn_s_setprio(1);
            #pragma unroll
            for (int mi = 0; mi < MI; ++mi)
                #pragma unroll
                for (int ni = 0; ni < NI; ++ni)
                    acc[mi][ni] = __builtin_amdgcn_mfma_f32_16x16x32_bf16(af[mi], bfr[ni], acc[mi][ni], 0, 0, 0);
            __builtin_amdgcn_s_setprio(0);
        };

        #pragma unroll
        for (int d = 0; d < 3; ++d) {
            stageA(d, d << 6);
            stageB(d, d << 6);
        }
        #pragma unroll 1
        for (int kt = 0; kt < nk; ++kt) {
            int b = kt & 3;
            if (kt + 3 < nk) {
                int bb = (kt + 3) & 3;
                stageA(bb, (kt + 3) << 6);
                stageB(bb, (kt + 3) << 6);
            }
            int rem = nk - 1 - kt;
            if (rem >= 3)      asm volatile("s_waitcnt vmcnt(12)\ns_barrier" ::: "memory");
            else if (rem == 2) asm volatile("s_waitcnt vmcnt(8)\ns_barrier" ::: "memory");
            else if (rem == 1) asm volatile("s_waitcnt vmcnt(4)\ns_barrier" ::: "memory");
            else               asm volatile("s_waitcnt vmcnt(0)\ns_barrier" ::: "memory");
            compute_half(As[b], Bs[b], seg0);
            compute_half(As[b], Bs[b], seg1);
            asm volatile("s_barrier" ::: "memory");
        }
    }

    if constexpr (EPI == 4) {
        int sel = bn >> 10;                        // block-uniform (BN <= 1024)
        int row_base = bm + wr * (BM / 2) + q * 4; // +mi*16+r
        int l0 = row_base & (LL - 1);              // same b for whole block
        const float2* tbl = (const float2*)(sel == 0 ? bias : R_);  // TQ / TK
        #pragma unroll
        for (int ni = 0; ni < NI; ++ni) {
            int col = bn + wc * (BN / 4) + ni * 16 + lr;
            int cq = col & (DIM - 1);
            if (sel <= 1) {
                int jj = (col & 127) >> 1;
                short* Ob = (short*)(sel == 0 ? Cv : P1);
                #pragma unroll
                for (int mi = 0; mi < MI; ++mi) {
                    #pragma unroll
                    for (int r = 0; r < 4; ++r) {
                        int l = l0 + mi * 16 + r;
                        float2 t = tbl[((size_t)l << 6) + jj];
                        float v = acc[mi][ni][r];
                        float p = __shfl_xor(v, 1);
                        float o = (lr & 1) ? (v * t.x + p * t.y) : (v * t.x - p * t.y);
                        Ob[(size_t)(row_base + mi * 16 + r) * DIM + cq] = f2bf(o);
                    }
                }
            } else if (sel == 2) {
                short* Vb = (short*)P2;
                #pragma unroll
                for (int mi = 0; mi < MI; ++mi)
                    #pragma unroll
                    for (int r = 0; r < 4; ++r)
                        Vb[(size_t)(row_base + mi * 16 + r) * DIM + cq] = f2bf(acc[mi][ni][r]);
            } else {
                short* Gb = (short*)P3;
                #pragma unroll
                for (int mi = 0; mi < MI; ++mi)
                    #pragma unroll
                    for (int r = 0; r < 4; ++r)
                        Gb[(size_t)(row_base + mi * 16 + r) * DIM + cq] = f2bf(acc[mi][ni][r]);
            }
        }
        return;
    }

    float* Cf = (float*)Cv;
    short* Cs = (short*)Cv;
    #pragma unroll
    for (int ni = 0; ni < NI; ++ni) {
        int col = bn + wc * (BN / 4) + ni * 16 + lr;
        float bi = 0.f;
        if constexpr (EPI == 1 || EPI == 2) bi = bias[col];
        #pragma unroll
        for (int mi = 0; mi < MI; ++mi) {
            int row0 = bm + wr * (BM / 2) + mi * 16 + q * 4;
            #pragma unroll
            for (int r = 0; r < 4; ++r) {
                size_t off = (size_t)(row0 + r) * M + col;
                float v = acc[mi][ni][r];
                if constexpr (EPI == 1) {
                    v += bi;
                    v = 0.5f * v * (1.f + erff(v * 0.70710678118654752f));
                    Cs[off] = f2bf(v);
                } else if constexpr (EPI == 2) {
                    Cf[off] = v + bi + R_[off];
                } else if constexpr (EPI == 3) {
                    Cf[off] = v + R_[off];
                } else {
                    Cf[off] = v;
                }
            }
        }
    }
}

// ---------------- retention: 8-wave parity-split, counted-vmcnt pipeline ----------------
#define PSTR 40
__global__ __launch_bounds__(512, 2) void retention_mfma2(
    const short* __restrict__ Qb, const short* __restrict__ Kb,
    const short* __restrict__ Vt, float* __restrict__ Y)
{
    __shared__ __align__(16) short Ks[2][64 * 128];   // 32 KB (also Y-combine scratch)
    __shared__ __align__(16) short Vs[2][128 * 64];   // 32 KB
    __shared__ __align__(16) short Ps[8][16 * PSTR];  // 10 KB
    int tid = threadIdx.x;
    int w = tid >> 6, lane = tid & 63;
    int q = lane >> 4, lr = lane & 15;
    int g = w >> 2;                        // tile-parity group
    int qw = w & 3;                        // Q sub-strip wave
    int bh = blockIdx.x;
    int b = bh >> 3, h = bh & 7;
    size_t bL = (size_t)b * LL;
    const short* Kbh = Kb + (bL << 10) + (h << 7);
    const short* Qbh = Qb + (bL << 10) + (h << 7);
    const short* Vbh = Vt + ((size_t)bh << 18);
    float* Ybh = Y + (bL << 10) + (h << 7);

    const float lg_lo = -3.4657359027997265f;
    const float lg_hi = -6.2383246250395075f;
    float gamma = 1.f - expf(lg_lo + (lg_hi - lg_lo) * ((float)h / 7.f));
    float logg = logf(gamma);
    float gm64 = expf(-64.f * logg);
    float rf[4];
    #pragma unroll
    for (int r = 0; r < 4; ++r) rf[r] = expf(logg * (float)(q * 4 + r));
    float cf0 = expf(-logg * (float)lr);
    float cf1 = expf(-logg * (float)(16 + lr));
    int dqlr = q * 4 - lr;

    int kr_l = lane >> 4;                  // 0..3
    int ks_l = lane & 15;                  // 16B seg in 256B row
    int vr_l = lane >> 3;                  // 0..7
    int vs_l = lane & 7;                   // 16B seg in 128B row

    auto stageKV = [&](int bb, int m0) {
        #pragma unroll
        for (int i = 0; i < 2; ++i) {
            int ch = w * 2 + i;            // 0..15
            int kr = ch * 4 + kr_l;        // 0..63
            gl_lds16(Kbh + ((size_t)(m0 + kr) << 10) + ((ks_l ^ (kr & 15)) << 3),
                     &Ks[bb][ch * 512]);
            int vr = ch * 8 + vr_l;        // 0..127
            gl_lds16(Vbh + ((size_t)vr << 11) + m0 + ((vs_l ^ (vr & 7)) << 3),
                     &Vs[bb][ch * 512]);
        }
    };

    #pragma unroll 1
    for (int pass = 0; pass < 2; ++pass) {
        int jt = pass ? (31 - blockIdx.y) : blockIdx.y;
        int l0w = jt * 64 + qw * 16;
        int ns = jt + 1;                   // 64-row K/V steps

        bf16x8 qf[4];
        {
            const short* qp = Qbh + ((size_t)(l0w + lr) << 10) + q * 8;
            #pragma unroll
            for (int es = 0; es < 4; ++es) qf[es] = *(const bf16x8*)(qp + es * 32);
        }
        f32x4 yacc[8];
        #pragma unroll
        for (int vt = 0; vt < 8; ++vt) yacc[vt] = (f32x4){0.f, 0.f, 0.f, 0.f};
        float tf = expf(logg * (float)(l0w - g * 32));

        stageKV(0, 0);

        #pragma unroll 1
        for (int s = 0; s < ns; ++s) {
            int buf = s & 1;
            if (s + 1 < ns) {
                stageKV(buf ^ 1, (s + 1) * 64);
                asm volatile("s_waitcnt vmcnt(4)\ns_barrier" ::: "memory");
            } else {
                asm volatile("s_waitcnt vmcnt(0)\ns_barrier" ::: "memory");
            }
            int m0 = s * 64 + g * 32;
            if (m0 <= l0w + 15) {
                int dt = l0w - m0;
                const short* ksub = &Ks[buf][g * 32 * 128];
                f32x4 sa0 = (f32x4){0.f,0.f,0.f,0.f};
                f32x4 sa1 = (f32x4){0.f,0.f,0.f,0.f};
                #pragma unroll
                for (int es = 0; es < 4; ++es) {
                    int slot = ((es * 4 + q) ^ lr) * 8;
                    bf16x8 bk0 = *(const bf16x8*)&ksub[lr * 128 + slot];
                    bf16x8 bk1 = *(const bf16x8*)&ksub[(16 + lr) * 128 + slot];
                    sa0 = __builtin_amdgcn_mfma_f32_16x16x32_bf16(qf[es], bk0, sa0, 0, 0, 0);
                    sa1 = __builtin_amdgcn_mfma_f32_16x16x32_bf16(qf[es], bk1, sa1, 0, 0, 0);
                }
                #pragma unroll
                for (int r = 0; r < 4; ++r) {
                    float p0 = sa0[r] * (rf[r] * cf0 * tf);
                    float p1 = sa1[r] * (rf[r] * cf1 * tf);
                    int d0 = dt + dqlr + r;
                    Ps[w][(q*4 + r) * PSTR + lr]      = (d0 >= 0)      ? f2bf(p0) : (short)0;
                    Ps[w][(q*4 + r) * PSTR + 16 + lr] = (d0 - 16 >= 0) ? f2bf(p1) : (short)0;
                }
                bf16x8 pa = *(const bf16x8*)&Ps[w][lr * PSTR + q * 8];
                #pragma unroll
                for (int vt = 0; vt < 8; ++vt) {
                    bf16x8 bv = *(const bf16x8*)&Vs[buf][(vt * 16 + lr) * 64 + (((g * 4 + q) ^ (lr & 7)) << 3)];
                    yacc[vt] = __builtin_amdgcn_mfma_f32_16x16x32_bf16(pa, bv, yacc[vt], 0, 0, 0);
                }
            }
            tf *= gm64;
            asm volatile("s_barrier" ::: "memory");
        }
        __syncthreads();
        // combine group partials via LDS scratch (reuse Ks; xor-swizzled, 2-way free)
        float* sc = (float*)&Ks[0][0] + qw * 2048;
        if (g) {
            #pragma unroll
            for (int vt = 0; vt < 8; ++vt)
                #pragma unroll
                for (int r = 0; r < 4; ++r)
                    sc[(q * 4 + r) * 128 + ((vt * 16 + lr) ^ (q * 8))] = yacc[vt][r];
        }
        __syncthreads();
        if (!g) {
            float* yp = Ybh + ((size_t)(l0w + q * 4) << 10) + lr;
            #pragma unroll
            for (int vt = 0; vt < 8; ++vt)
                #pragma unroll
                for (int r = 0; r < 4; ++r)
                    yp[((size_t)r << 10) + vt * 16] =
                        yacc[vt][r] + sc[(q * 4 + r) * 128 + ((vt * 16 + lr) ^ (q * 8))];
        }
        __syncthreads();
    }
}

// ---------------- groupnorm * swish-gate (bf16 G) -> bf16 out ----------------
__global__ __launch_bounds__(256) void gn_gate_kernel(
    const float* __restrict__ Y, const short* __restrict__ Gb,
    const float* __restrict__ w, const float* __restrict__ b,
    short* __restrict__ ybf)
{
    int tid = threadIdx.x;
    int wid = tid >> 6, lane = tid & 63;
    int grp = blockIdx.x * 4 + wid;
    int n = grp >> 3, h = grp & 7;
    size_t base = (size_t)n * DIM + h * HD + lane * 2;
    float2 y = *(const float2*)(Y + base);
    float s = y.x + y.y, ss = y.x * y.x + y.y * y.y;
    #pragma unroll
    for (int o = 32; o > 0; o >>= 1) { s += __shfl_down(s, o); ss += __shfl_down(ss, o); }
    s = __shfl(s, 0); ss = __shfl(ss, 0);
    float mu  = s * (1.f / HD);
    float var = ss * (1.f / HD) - mu * mu;
    float rs  = rsqrtf(var + 1e-5f);
    float2 wv = *(const float2*)(w + h * HD + lane * 2);
    float2 bv = *(const float2*)(b + h * HD + lane * 2);
    bf16x2 gv = *(const bf16x2*)(Gb + base);
    float gx = bf2f(gv[0]), gy = bf2f(gv[1]);
    float g0 = gx / (1.f + expf(-gx));
    float g1 = gy / (1.f + expf(-gy));
    bf16x2 o;
    o[0] = f2bf(((y.x - mu) * rs * wv.x + bv.x) * g0);
    o[1] = f2bf(((y.y - mu) * rs * wv.y + bv.y) * g1);
    *(bf16x2*)(ybf + base) = o;
}

extern "C" void kernel_launch(void* const* d_in, const int* in_sizes, int n_in,
                              void* d_out, int out_size, void* d_ws, size_t ws_size,
                              hipStream_t stream)
{
    const float* X0   = (const float*)d_in[0];
    const float* Wq   = (const float*)d_in[1];
    const float* Wk   = (const float*)d_in[2];
    const float* Wv   = (const float*)d_in[3];
    const float* WG   = (const float*)d_in[4];
    const float* WO   = (const float*)d_in[5];
    const float* gnw  = (const float*)d_in[6];
    const float* gnb  = (const float*)d_in[7];
    const float* ln1w = (const float*)d_in[8];
    const float* ln1b = (const float*)d_in[9];
    const float* ln2w = (const float*)d_in[10];
    const float* ln2b = (const float*)d_in[11];
    const float* fw1  = (const float*)d_in[12];
    const float* fb1  = (const float*)d_in[13];
    const float* fw2  = (const float*)d_in[14];
    const float* fb2  = (const float*)d_in[15];

    float* ws = (float*)d_ws;
    const size_t U = (size_t)NROWS * DIM;    // 4M floats = 16 MB

    short* lnbf  = (short*)(ws + 0 * U);
    short* wqkvg = lnbf + (size_t)NROWS * DIM;
    short* Vt   = (short*)(ws + 1 * U);
    short* fw1t = (short*)(ws + 1 * U);
    short* fw2t = fw1t + (size_t)DIM * FFN_DIM;
    float* sY  = ws + 2 * U;
    short* h1   = (short*)(ws + 2 * U);              // 32 MB spans U2+U3
    short* Vb   = (short*)(ws + 3 * U);
    short* ybf  = (short*)(ws + 3 * U);
    short* wot  = ybf + (size_t)NROWS * DIM;
    short* Gb   = (short*)(ws + 4 * U);
    float* sXn = ws + 4 * U;                         // after gn_gate, Gb dead
    short* Qb   = (short*)(ws + 5 * U);
    short* Kb   = Qb + (size_t)NROWS * DIM;
    float* sX  = ws + 6 * U;
    // xpos tables live in the first 2 MB of U2 (free until retention writes sY;
    // only read during the QKVG epilogue). Rebuilt each layer.
    float2* tqg = (float2*)(ws + 2 * U);             // 1 MB (2048*64 float2)
    float2* tkg = tqg + (size_t)LL * 64;             // 1 MB

    for (int i = 0; i < 2; ++i) {
        const float* Xin = (i == 0) ? X0 : sX;
        float* Xout = (i == 1) ? (float*)d_out : sX;

        // LN1 -> bf16
        ln_kernel_bf<<<NROWS, 256, 0, stream>>>(Xin, ln1w + i * DIM, ln1b + i * DIM, lnbf);
        // weight transposes into one contiguous (4096,1024) Bt: [Wq|Wk|Wv|WG]
        dim3 tq(HD / 32, DIM / 32, HEADS);
        transpose_cvt<<<tq, 256, 0, stream>>>(Wq + (size_t)i * HEADS * DIM * HD, wqkvg + 0 * DIM * DIM, DIM, HD, (size_t)DIM * HD, (size_t)HD * DIM);
        transpose_cvt<<<tq, 256, 0, stream>>>(Wk + (size_t)i * HEADS * DIM * HD, wqkvg + 1 * DIM * DIM, DIM, HD, (size_t)DIM * HD, (size_t)HD * DIM);
        transpose_cvt<<<tq, 256, 0, stream>>>(Wv + (size_t)i * HEADS * DIM * HD, wqkvg + 2 * DIM * DIM, DIM, HD, (size_t)DIM * HD, (size_t)HD * DIM);
        dim3 tg(DIM / 32, DIM / 32, 1);
        transpose_cvt<<<tg, 256, 0, stream>>>(WG + (size_t)i * DIM * DIM, wqkvg + 3 * (size_t)DIM * DIM, DIM, DIM, 0, 0);
        // xpos tables (U2 currently dead)
        xpos_tables<<<LL * 64 / 256, 256, 0, stream>>>(tqg, tkg);
        // fused QKVG projection + xpos + bf16: writes Qb, Kb, Vb, Gb (256^2, 8-phase)
        dim3 gp4(4 * DIM / 256, NROWS / 256);   // (16,16)
        gemm_pipe<4, 8, 4, 16><<<gp4, 512, 0, stream>>>(lnbf, wqkvg, Qb, (const float*)tqg, (const float*)tkg, Kb, Vb, Gb, NROWS, DIM, 4 * DIM);
        // V transpose (bf16 -> bf16 [bh][v][l])
        dim3 vg(DIM / 32, NROWS / 32);
        vt_cvt<<<vg, 256, 0, stream>>>(Vb, Vt);
        // retention -> sY (8-wave parity-split)
        dim3 rg(16, 16);
        retention_mfma2<<<rg, 512, 0, stream>>>(Qb, Kb, Vt, sY);
        // groupnorm + gate -> ybf (overwrites Vb region; Vb dead)
        gn_gate_kernel<<<NROWS * HEADS / 4, 256, 0, stream>>>(sY, Gb, gnw + i * DIM, gnb + i * DIM, ybf);
        // W_O + residual -> sXn (Gb dead)
        transpose_cvt<<<tg, 256, 0, stream>>>(WO + (size_t)i * DIM * DIM, wot, DIM, DIM, 0, 0);
        dim3 gp(DIM / 128, NROWS / 128);   // (8,32)
        gemm_pipe<3, 4, 2, 8><<<gp, 512, 0, stream>>>(ybf, wot, sXn, nullptr, Xin, nullptr, nullptr, nullptr, NROWS, DIM, DIM);
        // LN2 -> lnbf
        ln_kernel_bf<<<NROWS, 256, 0, stream>>>(sXn, ln2w + i * DIM, ln2b + i * DIM, lnbf);
        // FFN weight transposes (U1 free: Vt dead after retention)
        dim3 t1(FFN_DIM / 32, DIM / 32, 1);
        transpose_cvt<<<t1, 256, 0, stream>>>(fw1 + (size_t)i * DIM * FFN_DIM, fw1t, DIM, FFN_DIM, 0, 0);
        dim3 t2(DIM / 32, FFN_DIM / 32, 1);
        transpose_cvt<<<t2, 256, 0, stream>>>(fw2 + (size_t)i * FFN_DIM * DIM, fw2t, FFN_DIM, DIM, 0, 0);
        // FFN1: + bias + gelu -> h1 bf16 (256^2, 8-phase)
        dim3 gf1(FFN_DIM / 256, NROWS / 256);   // (16,16)
        gemm_pipe<1, 8, 4, 16><<<gf1, 512, 0, stream>>>(lnbf, fw1t, h1, fb1 + i * FFN_DIM, nullptr, nullptr, nullptr, nullptr, NROWS, DIM, FFN_DIM);
        // FFN2: + bias + residual -> Xout fp32
        dim3 gf2(DIM / 128, NROWS / 128);       // (8,32)
        gemm_pipe<2, 4, 2, 8><<<gf2, 512, 0, stream>>>(h1, fw2t, Xout, fb2 + i * DIM, sXn, nullptr, nullptr, nullptr, NROWS, FFN_DIM, DIM);
    }
}